// Round 15
// baseline (4095.549 us; speedup 1.0000x reference)
//
#include <hip/hip_runtime.h>

#define SEQ 512
#define BB 64
#define IN_DIM 128
#define HH 256
#define NL 6
#define G3 768
#define CHUNK 8
#define NCH (SEQ/CHUNK)   // 64
#define FSTR 16           // ints per flag line

typedef short short8 __attribute__((ext_vector_type(8)));
typedef short short4v __attribute__((ext_vector_type(4)));
typedef float f32x4 __attribute__((ext_vector_type(4)));

// ws: fring[5][4][8][64][256] bf16 | xg[6][2][8][4][768][16] bf16 | flags  (~30.4 MB, R12-proven)
#define FR_SH ((size_t)5*4*CHUNK*BB*HH)
#define XG_SH ((size_t)NL*2*CHUNK*4*G3*16)
#define FLAGS_OFF_B ((FR_SH + XG_SH)*2)
#define NFLAG_INTS (16 + (24 + 96)*FSTR)
#define XGI(L,CS,TS,GI) (((((size_t)(L)*2+(CS))*CHUNK+(TS))*4+(GI))*((size_t)G3*16))

__device__ __forceinline__ short f2bf(float f) {
    unsigned u = __builtin_bit_cast(unsigned, f);
    u += 0x7fffu + ((u >> 16) & 1u);   // RNE
    return (short)(u >> 16);
}
__device__ __forceinline__ float b2f(short s) {
    unsigned u = ((unsigned)(unsigned short)s) << 16;
    return __builtin_bit_cast(float, u);
}
__device__ __forceinline__ float sigm(float v) { return __fdividef(1.f, 1.f + __expf(-v)); }
__device__ __forceinline__ float tanh_f(float v) { float e = __expf(2.f * v); return 1.f - __fdividef(2.f, e + 1.f); }

__device__ __forceinline__ short8 pack_row(const float* p) {
    float4 a = *(const float4*)p;
    float4 c = *(const float4*)(p + 4);
    short8 v;
    v[0] = f2bf(a.x); v[1] = f2bf(a.y); v[2] = f2bf(a.z); v[3] = f2bf(a.w);
    v[4] = f2bf(c.x); v[5] = f2bf(c.y); v[6] = f2bf(c.z); v[7] = f2bf(c.w);
    return v;
}

struct XgRegs { short4v r0, r1, z0, z1, n0, n1; };
// async sc0 (L1-bypass) loads; caller MUST s_waitcnt vmcnt(0) + sched_barrier
// before ANY use (including register copies) of the outputs.
__device__ __forceinline__ XgRegs ld_xg(const short* pR, const short* pZ, const short* pN) {
    XgRegs o;
    asm volatile(
        "global_load_dwordx2 %0, %6, off sc0\n\t"
        "global_load_dwordx2 %1, %6, off offset:512 sc0\n\t"
        "global_load_dwordx2 %2, %7, off sc0\n\t"
        "global_load_dwordx2 %3, %7, off offset:512 sc0\n\t"
        "global_load_dwordx2 %4, %8, off sc0\n\t"
        "global_load_dwordx2 %5, %8, off offset:512 sc0"
        : "=&v"(o.r0), "=&v"(o.r1), "=&v"(o.z0), "=&v"(o.z1), "=&v"(o.n0), "=&v"(o.n1)
        : "v"(pR), "v"(pZ), "v"(pN) : "memory");
    return o;
}

__global__ __launch_bounds__(512, 1) void gru_persist(
    const float* __restrict__ x, const float* __restrict__ h0,
    const float* __restrict__ w_ih0, const float* __restrict__ w_ih_rest,
    const float* __restrict__ w_hh, const float* __restrict__ b_ih,
    const float* __restrict__ b_hh, float* __restrict__ y,
    short* __restrict__ fring, short* __restrict__ xg, int* __restrict__ flags)
{
    extern __shared__ char smem[];   // 147456 B -> 1 WG/CU
    const int tid = threadIdx.x;
    const unsigned long long ddl = __builtin_amdgcn_s_memrealtime() + 800000000ull; // ~8s

    const int xcc = __builtin_amdgcn_s_getreg(20 | (31 << 11)) & 0xf;  // HW_REG_XCC_ID
    if (xcc >= NL) return;
    __shared__ int s_slot;
    if (tid == 0) s_slot = __hip_atomic_fetch_add(&flags[xcc], 1, __ATOMIC_RELAXED, __HIP_MEMORY_SCOPE_AGENT);
    __syncthreads();
    const int slot = s_slot;
    if (slot >= 20) return;

    const int l = xcc;
    const int lane = tid & 63;
    const int wave = tid >> 6;      // 0..7
    const int q = lane >> 4;
    const int jj = lane & 15;

    int* recF  = flags + 16;                 // (l*4+g)*FSTR
    int* projF = flags + 16 + 24 * FSTR;     // (l*16+p)*FSTR

    if (slot < 4) {
        // ================= REC CU: layer l, batch group g =================
        const int g = slot;
        char* sWn = smem;                       // 8 waves x 2 n-tiles x 8 kt x 1024
        char* sHB = smem + 131072;              // 2 x 16 x 512 B swizzled bf16 h

        const float* whh = w_hh + (size_t)l * G3 * HH;
        short8 Wreg[4][8];
        #pragma unroll
        for (int i = 0; i < 4; ++i) {
            int row = (i >> 1) * HH + 32 * wave + 16 * (i & 1) + jj;
            #pragma unroll
            for (int kt = 0; kt < 8; ++kt)
                Wreg[i][kt] = pack_row(whh + (size_t)row * HH + kt * 32 + q * 8);
        }
        #pragma unroll
        for (int i2 = 0; i2 < 2; ++i2) {
            int row = 512 + 32 * wave + 16 * i2 + jj;
            #pragma unroll
            for (int kt = 0; kt < 8; ++kt) {
                short8 v = pack_row(whh + (size_t)row * HH + kt * 32 + q * 8);
                *(short8*)(sWn + ((size_t)(wave * 2 + i2) * 8 + kt) * 1024 + lane * 16) = v;
            }
        }
        float bhr[2], bhz[2], bhn2[2];
        #pragma unroll
        for (int jt2 = 0; jt2 < 2; ++jt2) {
            int j = 32 * wave + 16 * jt2 + jj;
            bhr[jt2]  = b_hh[l * G3 + j];
            bhz[jt2]  = b_hh[l * G3 + 256 + j];
            bhn2[jt2] = b_hh[l * G3 + 512 + j];
        }
        float hcur[2][4];
        #pragma unroll
        for (int jt2 = 0; jt2 < 2; ++jt2) {
            int j = 32 * wave + 16 * jt2 + jj;
            #pragma unroll
            for (int r = 0; r < 4; ++r)
                hcur[jt2][r] = h0[((size_t)l * BB + 16 * g + 4 * q + r) * HH + j];
        }
        for (int i = tid; i < 16 * 256; i += 512) {
            int b = i >> 8, j = i & 255;
            short hb = f2bf(h0[((size_t)l * BB + 16 * g + b) * HH + j]);
            *(short*)(sHB + b * 512 + ((2 * j) ^ ((b & 7) << 4))) = hb;
        }
        __syncthreads();

        const int cb = tid >> 5;                 // copy mapping: batch, j-block
        const int cj0 = (tid & 31) * 8;
        const int laneoff = (32 * wave + jj) * 16 + 4 * q;
        const size_t tsStride = (size_t)4 * G3 * 16;

        for (int c = 0; c < NCH; ++c) {
            // chunk wait (no acquire fence: xg read via sc0 from same-XCD L2)
            if (wave == 0) {
                const int* pa = nullptr; int tgt = 0;
                if (lane < 8) { pa = &projF[(l * 16 + 2 * lane + (g >> 1)) * FSTR]; tgt = c + 1; }
                else if (lane < 16 && l < NL - 1) { pa = &projF[((l + 1) * 16 + 2 * (lane - 8) + (g >> 1)) * FSTR]; tgt = c - 3; }
                int it = 0;
                for (;;) {
                    bool ok = true;
                    if (pa) ok = __hip_atomic_load((int*)pa, __ATOMIC_RELAXED, __HIP_MEMORY_SCOPE_AGENT) >= tgt;
                    if (__ballot(ok) == ~0ull) break;
                    __builtin_amdgcn_s_sleep(1);
                    if (((++it) & 63) == 0 && __builtin_amdgcn_s_memrealtime() > ddl) break;
                }
            }
            __syncthreads();

            short* frc = (l < NL - 1) ? fring + ((size_t)(l * 4 + (c & 3)) * CHUNK) * BB * HH : nullptr;
            const short* xgbase = xg + XGI(l, c & 1, 0, g);

            // prefetch ts=0 (chunk data fully published by proj)
            XgRegs xcur = ld_xg(xgbase + laneoff, xgbase + 256 * 16 + laneoff, xgbase + 512 * 16 + laneoff);

            for (int ts = 0; ts < CHUNK; ++ts) {
                const int t = c * CHUNK + ts;
                const int cur = t & 1, nxt = cur ^ 1;

                f32x4 acc[6] = {};   // 0,1=r  2,3=z  4,5=n
                #pragma unroll
                for (int kt = 0; kt < 8; ++kt) {
                    short8 af = *(const short8*)(sHB + cur * 8192 + (lane & 15) * 512
                                 + ((kt * 64 + q * 16) ^ ((lane & 7) << 4)));
                    acc[0] = __builtin_amdgcn_mfma_f32_16x16x32_bf16(af, Wreg[0][kt], acc[0], 0, 0, 0);
                    acc[1] = __builtin_amdgcn_mfma_f32_16x16x32_bf16(af, Wreg[1][kt], acc[1], 0, 0, 0);
                    acc[2] = __builtin_amdgcn_mfma_f32_16x16x32_bf16(af, Wreg[2][kt], acc[2], 0, 0, 0);
                    acc[3] = __builtin_amdgcn_mfma_f32_16x16x32_bf16(af, Wreg[3][kt], acc[3], 0, 0, 0);
                    short8 w4 = *(const short8*)(sWn + ((size_t)(wave * 2 + 0) * 8 + kt) * 1024 + lane * 16);
                    short8 w5 = *(const short8*)(sWn + ((size_t)(wave * 2 + 1) * 8 + kt) * 1024 + lane * 16);
                    acc[4] = __builtin_amdgcn_mfma_f32_16x16x32_bf16(af, w4, acc[4], 0, 0, 0);
                    acc[5] = __builtin_amdgcn_mfma_f32_16x16x32_bf16(af, w5, acc[5], 0, 0, 0);
                }
                // xcur loads (and prior copy stores) complete here; pin ordering so
                // NO use of xcur (even v_mov copies) floats above the wait (rule #18).
                asm volatile("s_waitcnt vmcnt(0)" ::: "memory");
                __builtin_amdgcn_sched_barrier(0);
                XgRegs xuse = xcur;                     // SAFE: values resident
                // re-issue prefetch for ts+1 into xcur (full step of latency cover)
                const int tn = (ts + 1 < CHUNK) ? ts + 1 : ts;
                const short* nb = xgbase + (size_t)tn * tsStride;
                xcur = ld_xg(nb + laneoff, nb + 256 * 16 + laneoff, nb + 512 * 16 + laneoff);

                #pragma unroll
                for (int jt2 = 0; jt2 < 2; ++jt2) {
                    int j = 32 * wave + 16 * jt2 + jj;
                    short4v xrv = jt2 ? xuse.r1 : xuse.r0;
                    short4v xzv = jt2 ? xuse.z1 : xuse.z0;
                    short4v xnv = jt2 ? xuse.n1 : xuse.n0;
                    #pragma unroll
                    for (int r = 0; r < 4; ++r) {
                        int b = 4 * q + r;
                        float rg = sigm(acc[jt2][r] + b2f(xrv[r]) + bhr[jt2]);
                        float zg = sigm(acc[2 + jt2][r] + b2f(xzv[r]) + bhz[jt2]);
                        float ng = tanh_f(b2f(xnv[r]) + rg * (acc[4 + jt2][r] + bhn2[jt2]));
                        float hn = ng + zg * (hcur[jt2][r] - ng);
                        hcur[jt2][r] = hn;
                        *(short*)(sHB + nxt * 8192 + b * 512 + ((2 * j) ^ ((b & 7) << 4))) = f2bf(hn);
                    }
                }
                __syncthreads();   // sHB[nxt] complete

                // coalesced copy of h(t)
                short8 hv = *(const short8*)(sHB + nxt * 8192 + cb * 512 + ((2 * cj0) ^ ((cb & 7) << 4)));
                if (l < NL - 1) {
                    *(short8*)(frc + ((size_t)ts * BB + 16 * g + cb) * HH + cj0) = hv;
                } else {
                    float4 f0, f1;
                    f0.x = b2f(hv[0]); f0.y = b2f(hv[1]); f0.z = b2f(hv[2]); f0.w = b2f(hv[3]);
                    f1.x = b2f(hv[4]); f1.y = b2f(hv[5]); f1.z = b2f(hv[6]); f1.w = b2f(hv[7]);
                    float* yd = y + ((size_t)t * BB + 16 * g + cb) * HH + cj0;
                    *(float4*)yd = f0;
                    *(float4*)(yd + 4) = f1;
                }
            }
            __syncthreads();       // drain copy stores before publish
            if (tid == 0)
                __hip_atomic_store(&recF[(l * 4 + g) * FSTR], c + 1, __ATOMIC_RELEASE, __HIP_MEMORY_SCOPE_AGENT);
        }
        // final hidden states (fp32 from regs)
        #pragma unroll
        for (int jt2 = 0; jt2 < 2; ++jt2) {
            int j = 32 * wave + 16 * jt2 + jj;
            #pragma unroll
            for (int r = 0; r < 4; ++r)
                y[(size_t)SEQ * BB * HH + (size_t)l * BB * HH + ((size_t)16 * g + 4 * q + r) * HH + j] = hcur[jt2][r];
        }
    } else {
        // ================= PROJ CU: layer l, p = slot-4 (R12 verbatim) =================
        const int p = slot - 4;
        const int t_p = p >> 1;
        const int bh = p & 1;
        const int KIN = (l == 0) ? IN_DIM : HH;
        const int KTp = (l == 0) ? 4 : 8;
        char* sWp = smem;

        const float* wih = (l == 0) ? w_ih0 : (w_ih_rest + (size_t)(l - 1) * G3 * HH);
        short8 Wp[4][8];
        #pragma unroll
        for (int i = 0; i < 4; ++i) {
            int row = (6 * wave + i) * 16 + jj;
            for (int kt = 0; kt < KTp; ++kt)
                Wp[i][kt] = pack_row(wih + (size_t)row * KIN + kt * 32 + q * 8);
        }
        #pragma unroll
        for (int i2 = 0; i2 < 2; ++i2) {
            int row = (6 * wave + 4 + i2) * 16 + jj;
            for (int kt = 0; kt < KTp; ++kt) {
                short8 v = pack_row(wih + (size_t)row * KIN + kt * 32 + q * 8);
                *(short8*)(sWp + ((size_t)(wave * 2 + i2) * 8 + kt) * 1024 + lane * 16) = v;
            }
        }
        float bias[6];
        #pragma unroll
        for (int i = 0; i < 6; ++i)
            bias[i] = b_ih[l * G3 + (6 * wave + i) * 16 + jj];
        __syncthreads();

        for (int c = 0; c < NCH; ++c) {
            if (wave == 0) {
                const int* pa = nullptr; int tgt = 0;
                if (lane < 2) { if (l > 0) { pa = &recF[((l - 1) * 4 + 2 * bh + lane) * FSTR]; tgt = c + 1; } }
                else if (lane < 4) { pa = &recF[(l * 4 + 2 * bh + (lane - 2)) * FSTR]; tgt = c - 1; }
                int it = 0;
                for (;;) {
                    bool ok = true;
                    if (pa) ok = __hip_atomic_load((int*)pa, __ATOMIC_RELAXED, __HIP_MEMORY_SCOPE_AGENT) >= tgt;
                    if (__ballot(ok) == ~0ull) break;
                    __builtin_amdgcn_s_sleep(1);
                    if (((++it) & 63) == 0 && __builtin_amdgcn_s_memrealtime() > ddl) break;
                }
                if (l > 0) __builtin_amdgcn_fence(__ATOMIC_ACQUIRE, "agent");
            }
            __syncthreads();

            const short* frs = (l > 0)
                ? fring + ((size_t)((l - 1) * 4 + (c & 3)) * CHUNK + t_p) * BB * HH : nullptr;

            #pragma unroll
            for (int mt2 = 0; mt2 < 2; ++mt2) {
                const int bgl = 32 * bh + 16 * mt2 + (lane & 15);
                short8 afv[8];
                for (int kt = 0; kt < KTp; ++kt) {
                    if (l == 0)
                        afv[kt] = pack_row(x + ((size_t)(c * CHUNK + t_p) * BB + bgl) * IN_DIM + kt * 32 + q * 8);
                    else
                        afv[kt] = *(const short8*)(frs + (size_t)bgl * HH + kt * 32 + q * 8);
                }
                f32x4 acc[6] = {};
                for (int kt = 0; kt < KTp; ++kt) {
                    short8 af = afv[kt];
                    acc[0] = __builtin_amdgcn_mfma_f32_16x16x32_bf16(af, Wp[0][kt], acc[0], 0, 0, 0);
                    acc[1] = __builtin_amdgcn_mfma_f32_16x16x32_bf16(af, Wp[1][kt], acc[1], 0, 0, 0);
                    acc[2] = __builtin_amdgcn_mfma_f32_16x16x32_bf16(af, Wp[2][kt], acc[2], 0, 0, 0);
                    acc[3] = __builtin_amdgcn_mfma_f32_16x16x32_bf16(af, Wp[3][kt], acc[3], 0, 0, 0);
                    short8 w4 = *(const short8*)(sWp + ((size_t)(wave * 2 + 0) * 8 + kt) * 1024 + lane * 16);
                    short8 w5 = *(const short8*)(sWp + ((size_t)(wave * 2 + 1) * 8 + kt) * 1024 + lane * 16);
                    acc[4] = __builtin_amdgcn_mfma_f32_16x16x32_bf16(af, w4, acc[4], 0, 0, 0);
                    acc[5] = __builtin_amdgcn_mfma_f32_16x16x32_bf16(af, w5, acc[5], 0, 0, 0);
                }
                short* xgd = xg + XGI(l, c & 1, t_p, 2 * bh + mt2);
                #pragma unroll
                for (int i = 0; i < 6; ++i) {
                    int r = (6 * wave + i) * 16 + jj;
                    short4v o;
                    o[0] = f2bf(acc[i][0] + bias[i]);
                    o[1] = f2bf(acc[i][1] + bias[i]);
                    o[2] = f2bf(acc[i][2] + bias[i]);
                    o[3] = f2bf(acc[i][3] + bias[i]);
                    *(short4v*)(xgd + (size_t)r * 16 + 4 * q) = o;   // plain store -> shared L2
                }
            }
            __syncthreads();   // drain xg stores before publish
            if (tid == 0)
                __hip_atomic_store(&projF[(l * 16 + p) * FSTR], c + 1, __ATOMIC_RELEASE, __HIP_MEMORY_SCOPE_AGENT);
        }
    }
}

extern "C" void kernel_launch(void* const* d_in, const int* in_sizes, int n_in,
                              void* d_out, int out_size, void* d_ws, size_t ws_size,
                              hipStream_t stream) {
    (void)in_sizes; (void)n_in; (void)out_size; (void)ws_size;
    const float* x         = (const float*)d_in[0];
    const float* h0        = (const float*)d_in[1];
    const float* w_ih0     = (const float*)d_in[2];
    const float* w_ih_rest = (const float*)d_in[3];
    const float* w_hh      = (const float*)d_in[4];
    const float* b_ih      = (const float*)d_in[5];
    const float* b_hh      = (const float*)d_in[6];
    float* y = (float*)d_out;

    short* fring = (short*)d_ws;
    short* xgb   = fring + FR_SH;
    int*   flags = (int*)((char*)d_ws + FLAGS_OFF_B);

    (void)hipMemsetAsync(flags, 0, NFLAG_INTS * sizeof(int), stream);
    gru_persist<<<256, 512, 147456, stream>>>(
        x, h0, w_ih0, w_ih_rest, w_hh, b_ih, b_hh, y, fring, xgb, flags);
}